// Round 5
// baseline (491.066 us; speedup 1.0000x reference)
//
#include <hip/hip_runtime.h>
#include <hip/hip_bf16.h>

#define Bb 4
#define Ss 2048
#define Dm 1024
#define Hh 16
#define DKk 64
#define DVv 64

using short8  = __attribute__((ext_vector_type(8))) short;
using short4v = __attribute__((ext_vector_type(4))) short;
using floatx4 = __attribute__((ext_vector_type(4))) float;

__device__ inline unsigned short f32_to_bf16(float f) {
    union { float f; unsigned int u; } x; x.f = f;
    unsigned int r = x.u + 0x7fffu + ((x.u >> 16) & 1u);
    return (unsigned short)(r >> 16);
}

// async global->LDS DMA, 16B per lane (dest = wave-uniform base + lane*16)
__device__ inline void dma16(const unsigned short* g, unsigned short* l) {
    __builtin_amdgcn_global_load_lds(
        (const __attribute__((address_space(1))) void*)g,
        (__attribute__((address_space(3))) void*)l, 16, 0, 0);
}

// ---------------------------------------------------------------------------
// Weight transpose + cast (all 4 weights in one launch, z selects):
// W (K=1024, N=1024) fp32 -> Wt (N, K) bf16
// ---------------------------------------------------------------------------
__global__ __launch_bounds__(256) void transpose_w4(
        const float* __restrict__ W0, const float* __restrict__ W1,
        const float* __restrict__ W2, const float* __restrict__ W3,
        unsigned short* __restrict__ T0, unsigned short* __restrict__ T1,
        unsigned short* __restrict__ T2, unsigned short* __restrict__ T3) {
    const float* W; unsigned short* Wt;
    switch (blockIdx.z) {
        case 0: W = W0; Wt = T0; break;
        case 1: W = W1; Wt = T1; break;
        case 2: W = W2; Wt = T2; break;
        default: W = W3; Wt = T3; break;
    }
    __shared__ float tile[32][33];
    int n0 = blockIdx.x * 32, k0 = blockIdx.y * 32;
    int tx = threadIdx.x, ty = threadIdx.y;   // (32, 8)
    #pragma unroll
    for (int i = 0; i < 32; i += 8)
        tile[ty + i][tx] = W[(size_t)(k0 + ty + i) * Dm + n0 + tx];
    __syncthreads();
    #pragma unroll
    for (int i = 0; i < 32; i += 8)
        Wt[(size_t)(n0 + ty + i) * Dm + k0 + tx] = f32_to_bf16(tile[tx][ty + i]);
}

// ---------------------------------------------------------------------------
// fp32 -> bf16 cast, 8 elements/thread (exact-fit grid, n = 8192*1024)
// ---------------------------------------------------------------------------
__global__ __launch_bounds__(256) void cast_bf16(const float* __restrict__ X,
                                                 unsigned short* __restrict__ Y) {
    const int idx = blockIdx.x * 256 + threadIdx.x;
    const float4* x4 = (const float4*)X;
    float4 f0 = x4[idx * 2], f1 = x4[idx * 2 + 1];
    const float* p0 = (const float*)&f0;
    const float* p1 = (const float*)&f1;
    union { short8 v; unsigned short u[8]; } o;
    #pragma unroll
    for (int j = 0; j < 4; j++) {
        o.u[j]     = f32_to_bf16(p0[j]);
        o.u[4 + j] = f32_to_bf16(p1[j]);
    }
    *(short8*)(Y + (size_t)idx * 8) = o.v;
}

// ---------------------------------------------------------------------------
// m97-structure GEMM: C = A (8192 x 1024 bf16) . Bt^T (+bias)
// 128x128 block tile, BK=32, global_load_lds staging, 2-barrier K-loop.
// mode 0: out bf16 [((bb*H+h)*S + s)*64 + d]                  (Q, K layout)
// mode 1: out bf16 [(((bb*H+h)*32 + s/64)*64 + d)*64 + s%64]  (V tile-blocked)
// ---------------------------------------------------------------------------
__global__ __launch_bounds__(256) void gemm_proj(const unsigned short* __restrict__ A,
                                                 const unsigned short* __restrict__ Bt,
                                                 const float* __restrict__ bias,
                                                 unsigned short* __restrict__ Out,
                                                 int mode) {
    const int wave = threadIdx.x >> 6;
    const int lane = threadIdx.x & 63;
    const int quad = lane >> 4;
    const int l16  = lane & 15;
    const int wr = wave & 1, wc = wave >> 1;
    const int m0 = blockIdx.x * 128;
    const int n0 = blockIdx.y * 128;

    __shared__ __align__(16) unsigned short Alds[4096];
    __shared__ __align__(16) unsigned short Blds[4096];

    const unsigned short* Asrc[2];
    const unsigned short* Bsrc[2];
    int Ldst[2];
    #pragma unroll
    for (int i = 0; i < 2; i++) {
        int L = (wave * 2 + i) * 64 + lane;
        int row = L >> 2, cpr = L & 3;
        int csrc = cpr ^ ((row >> 1) & 3);
        Ldst[i] = (wave * 2 + i) * 512;
        Asrc[i] = A  + (size_t)(m0 + row) * Dm + csrc * 8;
        Bsrc[i] = Bt + (size_t)(n0 + row) * Dm + csrc * 8;
    }

    int aoff[4], boff[4];
    #pragma unroll
    for (int r = 0; r < 4; r++) {
        int row = wr * 64 + r * 16 + l16;
        aoff[r] = row * 32 + (quad ^ ((row >> 1) & 3)) * 8;
        row = wc * 64 + r * 16 + l16;
        boff[r] = row * 32 + (quad ^ ((row >> 1) & 3)) * 8;
    }

    floatx4 acc[4][4] = {};

    for (int k0 = 0; k0 < Dm; k0 += 32) {
        __syncthreads();
        #pragma unroll
        for (int i = 0; i < 2; i++) {
            dma16(Asrc[i] + k0, &Alds[Ldst[i]]);
            dma16(Bsrc[i] + k0, &Blds[Ldst[i]]);
        }
        __syncthreads();

        short8 a[4], b[4];
        #pragma unroll
        for (int r = 0; r < 4; r++) a[r] = *(const short8*)(Alds + aoff[r]);
        #pragma unroll
        for (int c = 0; c < 4; c++) b[c] = *(const short8*)(Blds + boff[c]);
        #pragma unroll
        for (int r = 0; r < 4; r++)
            #pragma unroll
            for (int c = 0; c < 4; c++)
                acc[r][c] = __builtin_amdgcn_mfma_f32_16x16x32_bf16(a[r], b[c], acc[r][c], 0, 0, 0);
    }

    #pragma unroll
    for (int r = 0; r < 4; r++)
        #pragma unroll
        for (int c = 0; c < 4; c++) {
            int n = n0 + wc * 64 + c * 16 + l16;
            float bias_n = bias[n];
            int h = n >> 6, d = n & 63;
            #pragma unroll
            for (int i = 0; i < 4; i++) {
                int m = m0 + wr * 64 + r * 16 + quad * 4 + i;
                unsigned short ob = f32_to_bf16(acc[r][c][i] + bias_n);
                int bb = m >> 11, s = m & (Ss - 1);
                if (mode == 0)
                    Out[((size_t)(bb * Hh + h) * Ss + s) * 64 + d] = ob;
                else
                    Out[(((size_t)(bb * Hh + h) * 32 + (s >> 6)) * 64 + d) * 64 + (s & 63)] = ob;
            }
        }
}

// ---------------------------------------------------------------------------
// m97-structure final GEMM: AO (8192 x 1024 bf16) @ Wot^T + bo, * q_mask
// -> fp32 d_out
// ---------------------------------------------------------------------------
__global__ __launch_bounds__(256) void gemm_final(const unsigned short* __restrict__ A,
                                                  const unsigned short* __restrict__ Bt,
                                                  const float* __restrict__ bias,
                                                  const int* __restrict__ q_mask,
                                                  float* __restrict__ Out) {
    const int wave = threadIdx.x >> 6;
    const int lane = threadIdx.x & 63;
    const int quad = lane >> 4;
    const int l16  = lane & 15;
    const int wr = wave & 1, wc = wave >> 1;
    const int m0 = blockIdx.x * 128;
    const int n0 = blockIdx.y * 128;

    __shared__ __align__(16) unsigned short Alds[4096];
    __shared__ __align__(16) unsigned short Blds[4096];

    const unsigned short* Asrc[2];
    const unsigned short* Bsrc[2];
    int Ldst[2];
    #pragma unroll
    for (int i = 0; i < 2; i++) {
        int L = (wave * 2 + i) * 64 + lane;
        int row = L >> 2, cpr = L & 3;
        int csrc = cpr ^ ((row >> 1) & 3);
        Ldst[i] = (wave * 2 + i) * 512;
        Asrc[i] = A  + (size_t)(m0 + row) * Dm + csrc * 8;
        Bsrc[i] = Bt + (size_t)(n0 + row) * Dm + csrc * 8;
    }

    int aoff[4], boff[4];
    #pragma unroll
    for (int r = 0; r < 4; r++) {
        int row = wr * 64 + r * 16 + l16;
        aoff[r] = row * 32 + (quad ^ ((row >> 1) & 3)) * 8;
        row = wc * 64 + r * 16 + l16;
        boff[r] = row * 32 + (quad ^ ((row >> 1) & 3)) * 8;
    }

    floatx4 acc[4][4] = {};

    for (int k0 = 0; k0 < Dm; k0 += 32) {
        __syncthreads();
        #pragma unroll
        for (int i = 0; i < 2; i++) {
            dma16(Asrc[i] + k0, &Alds[Ldst[i]]);
            dma16(Bsrc[i] + k0, &Blds[Ldst[i]]);
        }
        __syncthreads();

        short8 a[4], b[4];
        #pragma unroll
        for (int r = 0; r < 4; r++) a[r] = *(const short8*)(Alds + aoff[r]);
        #pragma unroll
        for (int c = 0; c < 4; c++) b[c] = *(const short8*)(Blds + boff[c]);
        #pragma unroll
        for (int r = 0; r < 4; r++)
            #pragma unroll
            for (int c = 0; c < 4; c++)
                acc[r][c] = __builtin_amdgcn_mfma_f32_16x16x32_bf16(a[r], b[c], acc[r][c], 0, 0, 0);
    }

    #pragma unroll
    for (int r = 0; r < 4; r++)
        #pragma unroll
        for (int c = 0; c < 4; c++) {
            int n = n0 + wc * 64 + c * 16 + l16;
            float bias_n = bias[n];
            #pragma unroll
            for (int i = 0; i < 4; i++) {
                int m = m0 + wr * 64 + r * 16 + quad * 4 + i;
                float qm = (float)q_mask[m];
                Out[(size_t)m * Dm + n] = (acc[r][c][i] + bias_n) * qm;
            }
        }
}

// ---------------------------------------------------------------------------
// Flash attention: 128-query blocks (4 waves x 32 queries = 2 strips of 16),
// 64-key tiles, double-buffered global_load_lds K/V staging.
// Per wave-iter: 32 MFMA fed by one 16KB block DMA (2x compute density of r4).
// Waves skip compute (not DMA/barriers) for tiles fully above their queries.
// S^T = K . Q^T (C-layout: col=l16=query, row=quad*4+i=key); softmax
// reduction = 15 reg ops + 2 shuffles per strip; m/l one scalar/lane/strip.
// ---------------------------------------------------------------------------
#define PSTRIDE 72   // ushorts per P row (144 B) -> 2-way (free) b64/b128
#define SCL 0.18033688f      // 0.125 * log2(e)
#define PEN 1.44269504e12f   // 1e12 * log2(e)  (matches reference NEG_BIG)

__global__ __launch_bounds__(256) void attn_kernel(const unsigned short* __restrict__ Qp,
                                                   const unsigned short* __restrict__ Kp,
                                                   const unsigned short* __restrict__ Vt,
                                                   const int* __restrict__ v_mask,
                                                   unsigned short* __restrict__ AO) {
    const int wave = threadIdx.x >> 6;
    const int lane = threadIdx.x & 63;
    const int quad = lane >> 4;
    const int l16  = lane & 15;
    const int qt = (int)gridDim.x - 1 - (int)blockIdx.x;   // heavy tiles first
    const int h  = blockIdx.y;
    const int b  = blockIdx.z;
    const int bh = b * Hh + h;
    const int qbase = qt * 128 + wave * 32;     // wave owns [qbase, qbase+32)
    const int qmaxw = qbase + 31;

    __shared__ __align__(16) unsigned short Klds[2][4096];
    __shared__ __align__(16) unsigned short Vlds[2][4096];
    __shared__ __align__(16) unsigned short P_lds[4][32 * PSTRIDE];
    unsigned short* Pw = &P_lds[wave][0];

    int dmaOff[2], dmaDst[2];
    #pragma unroll
    for (int i = 0; i < 2; i++) {
        int G = (wave * 2 + i) * 64 + lane;
        int row = G >> 3, c = G & 7;
        dmaOff[i] = row * 64 + (c ^ (row & 7)) * 8;
        dmaDst[i] = (wave * 2 + i) * 512;
    }
    const unsigned short* Kt_base = Kp + (size_t)bh * Ss * 64;
    const unsigned short* Vt_base = Vt + (size_t)bh * 32 * 4096;

    // Q B-fragments for both strips (n = query = strip*16 + l16)
    short8 qf[2][2];
    #pragma unroll
    for (int s = 0; s < 2; s++) {
        const unsigned short* qp = Qp + ((size_t)bh * Ss + qbase + s * 16 + l16) * 64 + quad * 8;
        qf[s][0] = *(const short8*)(qp);
        qf[s][1] = *(const short8*)(qp + 32);
    }

    const int slot0 = (quad ^ (l16 & 7)) * 8;
    const int slot1 = slot0 ^ 32;

    floatx4 o[2][4] = {};
    float mrun[2] = {-3e38f, -3e38f};
    float lrun[2] = {0.f, 0.f};

    #pragma unroll
    for (int i = 0; i < 2; i++) {
        dma16(Kt_base + dmaOff[i], &Klds[0][dmaDst[i]]);
        dma16(Vt_base + dmaOff[i], &Vlds[0][dmaDst[i]]);
    }
    __syncthreads();

    const int ktmax = 2 * qt + 1;
    int cur = 0;
    for (int kt = 0; kt <= ktmax; kt++) {
        if (kt < ktmax) {
            const unsigned short* kn = Kt_base + (size_t)(kt + 1) * 4096;
            const unsigned short* vn = Vt_base + (size_t)(kt + 1) * 4096;
            #pragma unroll
            for (int i = 0; i < 2; i++) {
                dma16(kn + dmaOff[i], &Klds[cur ^ 1][dmaDst[i]]);
                dma16(vn + dmaOff[i], &Vlds[cur ^ 1][dmaDst[i]]);
            }
        }

        const int kk = kt * 64;
        if (kk <= qmaxw) {   // tile not entirely above this wave's queries
            const unsigned short* Kc = &Klds[cur][0];
            const unsigned short* Vc = &Vlds[cur][0];

            // --- S^T = K . Q^T for both query strips (K frags shared) ---
            floatx4 st[4][2];
            #pragma unroll
            for (int kf = 0; kf < 4; kf++) {
                const unsigned short* kp = Kc + (kf * 16 + l16) * 64;
                short8 a0 = *(const short8*)(kp + slot0);
                short8 a1 = *(const short8*)(kp + slot1);
                #pragma unroll
                for (int s = 0; s < 2; s++) {
                    floatx4 t = {};
                    t = __builtin_amdgcn_mfma_f32_16x16x32_bf16(a0, qf[s][0], t, 0, 0, 0);
                    t = __builtin_amdgcn_mfma_f32_16x16x32_bf16(a1, qf[s][1], t, 0, 0, 0);
                    st[kf][s] = t;
                }
            }

            // --- mask penalties (shared across strips) ---
            float pen[4][4];
            #pragma unroll
            for (int kf = 0; kf < 4; kf++) {
                const int4 vm = *(const int4*)(v_mask + b * Ss + kk + kf * 16 + quad * 4);
                pen[kf][0] = (vm.x == 0) ? PEN : 0.f;
                pen[kf][1] = (vm.y == 0) ? PEN : 0.f;
                pen[kf][2] = (vm.z == 0) ? PEN : 0.f;
                pen[kf][3] = (vm.w == 0) ? PEN : 0.f;
            }

            // --- per-strip online softmax + P pack + O rescale ---
            #pragma unroll
            for (int s = 0; s < 2; s++) {
                const int query = qbase + s * 16 + l16;
                float sv[4][4];
                float mloc = -3e38f;
                #pragma unroll
                for (int kf = 0; kf < 4; kf++)
                    #pragma unroll
                    for (int i = 0; i < 4; i++) {
                        const int key = kk + kf * 16 + quad * 4 + i;
                        float p = pen[kf][i];
                        if (key > query) p += PEN;
                        sv[kf][i] = fmaf(st[kf][s][i], SCL, -p);
                        mloc = fmaxf(mloc, sv[kf][i]);
                    }
                mloc = fmaxf(mloc, __shfl_xor(mloc, 16, 64));
                mloc = fmaxf(mloc, __shfl_xor(mloc, 32, 64));
                const float mnew = fmaxf(mrun[s], mloc);
                const float alpha = exp2f(mrun[s] - mnew);
                mrun[s] = mnew;

                float ps = 0.f;
                #pragma unroll
                for (int kf = 0; kf < 4; kf++) {
                    union { short4v v; unsigned short u[4]; } pk;
                    #pragma unroll
                    for (int i = 0; i < 4; i++) {
                        const float p = exp2f(sv[kf][i] - mnew);
                        ps += p;
                        pk.u[i] = f32_to_bf16(p);
                    }
                    *(short4v*)(Pw + (s * 16 + l16) * PSTRIDE + kf * 16 + quad * 4) = pk.v;
                }
                ps += __shfl_xor(ps, 16, 64);
                ps += __shfl_xor(ps, 32, 64);
                lrun[s] = lrun[s] * alpha + ps;

                float ai[4];
                #pragma unroll
                for (int i = 0; i < 4; i++)
                    ai[i] = __shfl(alpha, quad * 4 + i, 64);
                #pragma unroll
                for (int f = 0; f < 4; f++)
                    #pragma unroll
                    for (int i = 0; i < 4; i++)
                        o[s][f][i] *= ai[i];
            }

            // --- P A-frags (both strips), then PV with shared V frags ---
            short8 pa[2][2];
            #pragma unroll
            for (int s = 0; s < 2; s++) {
                pa[s][0] = *(const short8*)(Pw + (s * 16 + l16) * PSTRIDE + quad * 8);
                pa[s][1] = *(const short8*)(Pw + (s * 16 + l16) * PSTRIDE + 32 + quad * 8);
            }
            #pragma unroll
            for (int f = 0; f < 4; f++) {
                const unsigned short* vp = Vc + (f * 16 + l16) * 64;
                short8 v0 = *(const short8*)(vp + slot0);
                short8 v1 = *(const short8*)(vp + slot1);
                #pragma unroll
                for (int s = 0; s < 2; s++) {
                    o[s][f] = __builtin_amdgcn_mfma_f32_16x16x32_bf16(pa[s][0], v0, o[s][f], 0, 0, 0);
                    o[s][f] = __builtin_amdgcn_mfma_f32_16x16x32_bf16(pa[s][1], v1, o[s][f], 0, 0, 0);
                }
            }
        }

        __syncthreads();
        cur ^= 1;
    }

    // epilogue: divide by row sums, write (B, S, H*64) bf16
    #pragma unroll
    for (int s = 0; s < 2; s++) {
        float ri[4];
        #pragma unroll
        for (int i = 0; i < 4; i++)
            ri[i] = 1.0f / __shfl(lrun[s], quad * 4 + i, 64);
        #pragma unroll
        for (int f = 0; f < 4; f++) {
            const int d = h * 64 + f * 16 + l16;
            #pragma unroll
            for (int i = 0; i < 4; i++) {
                const float val = o[s][f][i] * ri[i];
                AO[((size_t)b * Ss + qbase + s * 16 + quad * 4 + i) * (Hh * DVv) + d] = f32_to_bf16(val);
            }
        }
    }
}

// ---------------------------------------------------------------------------
extern "C" void kernel_launch(void* const* d_in, const int* in_sizes, int n_in,
                              void* d_out, int out_size, void* d_ws, size_t ws_size,
                              hipStream_t stream) {
    const float* q      = (const float*)d_in[0];
    const float* k      = (const float*)d_in[1];
    const float* v      = (const float*)d_in[2];
    const int*   q_mask = (const int*)d_in[3];
    const int*   v_mask = (const int*)d_in[4];
    const float* Wq     = (const float*)d_in[5];
    const float* bq     = (const float*)d_in[6];
    const float* Wk     = (const float*)d_in[7];
    const float* bk     = (const float*)d_in[8];
    const float* Wv     = (const float*)d_in[9];
    const float* bv     = (const float*)d_in[10];
    const float* Wo     = (const float*)d_in[11];
    const float* bo     = (const float*)d_in[12];
    float* out = (float*)d_out;

    char* ws = (char*)d_ws;
    const size_t WT_SZ = (size_t)Dm * Dm * 2;                 // 2 MB each
    const size_t QP_SZ = (size_t)Bb * Hh * Ss * 64 * 2;       // 16 MB each
    unsigned short* Wtq = (unsigned short*)(ws);
    unsigned short* Wtk = (unsigned short*)(ws + WT_SZ);
    unsigned short* Wtv = (unsigned short*)(ws + 2 * WT_SZ);
    unsigned short* Wto = (unsigned short*)(ws + 3 * WT_SZ);
    unsigned short* Qp  = (unsigned short*)(ws + 4 * WT_SZ);
    unsigned short* Kp  = (unsigned short*)(ws + 4 * WT_SZ + QP_SZ);
    unsigned short* Vt  = (unsigned short*)(ws + 4 * WT_SZ + 2 * QP_SZ);
    unsigned short* AO  = (unsigned short*)(ws + 4 * WT_SZ + 3 * QP_SZ);
    // AO doubles as the bf16-cast scratch for q/k/v (dead until attn writes it)

    hipLaunchKernelGGL(transpose_w4, dim3(Dm / 32, Dm / 32, 4), dim3(32, 8), 0, stream,
                       Wq, Wk, Wv, Wo, Wtq, Wtk, Wtv, Wto);

    const int M = Bb * Ss;  // 8192
    const int castBlocks = M * Dm / (256 * 8);  // exact fit
    dim3 gg(M / 128, Dm / 128);

    hipLaunchKernelGGL(cast_bf16, dim3(castBlocks), dim3(256), 0, stream, q, AO);
    hipLaunchKernelGGL(gemm_proj, gg, dim3(256), 0, stream, AO, Wtq, bq, Qp, 0);
    hipLaunchKernelGGL(cast_bf16, dim3(castBlocks), dim3(256), 0, stream, k, AO);
    hipLaunchKernelGGL(gemm_proj, gg, dim3(256), 0, stream, AO, Wtk, bk, Kp, 0);
    hipLaunchKernelGGL(cast_bf16, dim3(castBlocks), dim3(256), 0, stream, v, AO);
    hipLaunchKernelGGL(gemm_proj, gg, dim3(256), 0, stream, AO, Wtv, bv, Vt, 1);

    dim3 ag(Ss / 128, Hh, Bb);
    hipLaunchKernelGGL(attn_kernel, ag, dim3(256), 0, stream, Qp, Kp, Vt, v_mask, AO);

    hipLaunchKernelGGL(gemm_final, gg, dim3(256), 0, stream, AO, Wto, bo, q_mask, out);
}